// Round 1
// baseline (47.509 us; speedup 1.0000x reference)
//
#include <hip/hip_runtime.h>

// LIF forward: u_t = u + (ir_t - u)/10 ; o_t = 1[u_t >= 1] ; (u_rest=0 -> no reset)
// One thread per float2 spatial element, sequential loop over T=100.
// Memory-bound streaming: ~210 MB total traffic, floor ~33 us @ 6.3 TB/s.

#define T_STEPS 100
#define BN      262144        // B*N = 32*8192
#define VEC     2
#define NTHR    (BN / VEC)    // 131072 threads

__global__ __launch_bounds__(256) void lif_fwd(const float2* __restrict__ ir,
                                               const float2* __restrict__ u0,
                                               float2* __restrict__ out) {
    const int idx = blockIdx.x * blockDim.x + threadIdx.x;   // 0..131071
    const int stride = BN / VEC;                             // float2 per time slab

    float2 u = u0[idx];

    // #pragma unroll 4: the 4 ir loads per unrolled group are address-independent
    // of the recurrence, so the compiler can issue them ahead (latency hiding at
    // 2 waves/SIMD occupancy).
    #pragma unroll 4
    for (int t = 0; t < T_STEPS; ++t) {
        const float2 ir_t = ir[(size_t)t * stride + idx];

        // Bitwise-match reference: u + (-(u - 0) + ir)/10  ==  u + (ir - u)/10.0f
        // (IEEE f32 division; no mul -> no FMA contraction hazard)
        u.x = u.x + (ir_t.x - u.x) / 10.0f;
        u.y = u.y + (ir_t.y - u.y) / 10.0f;

        float2 o;
        o.x = ((u.x - 1.0f) >= 0.0f) ? 1.0f : 0.0f;
        o.y = ((u.y - 1.0f) >= 0.0f) ? 1.0f : 0.0f;
        out[(size_t)t * stride + idx] = o;
        // u_next = u_t + u_rest * o_t = u_t  (u_rest == 0) -> nothing to do
    }
}

extern "C" void kernel_launch(void* const* d_in, const int* in_sizes, int n_in,
                              void* d_out, int out_size, void* d_ws, size_t ws_size,
                              hipStream_t stream) {
    const float2* ir = (const float2*)d_in[0];   // [T, B, N] f32
    const float2* u0 = (const float2*)d_in[1];   // [B, N] f32
    float2* out = (float2*)d_out;                // [T, B, N] f32

    lif_fwd<<<dim3(NTHR / 256), dim3(256), 0, stream>>>(ir, u0, out);
}

// Round 2
// 44.433 us; speedup vs baseline: 1.0692x; 1.0692x over previous
//
#include <hip/hip_runtime.h>

// LIF forward: u_t = u + (ir_t - u)/10 ; o_t = 1[u_t >= 1] ; u_rest=0 -> no reset.
// One thread per scalar element (VEC=1) -> 262144 threads = 16 waves/CU for
// latency hiding (prev float2 version was 8 waves/CU, 20% occupancy, 12% VALU).
// Non-temporal stores keep the 105 MB `out` stream from evicting the 105 MB
// `ir` slab out of the 256 MiB L3 across graph replays.

#define T_STEPS 100
#define BN      262144        // B*N = 32*8192
#define NTHR    BN            // one f32 per thread

__global__ __launch_bounds__(256) void lif_fwd(const float* __restrict__ ir,
                                               const float* __restrict__ u0,
                                               float* __restrict__ out) {
    const int idx = blockIdx.x * blockDim.x + threadIdx.x;   // 0..BN-1

    float u = u0[idx];

    // unroll 10: 10 address-independent ir loads can be issued ahead of the
    // dependent recurrence chain -> ~40 B/thread outstanding, 40 KB/CU.
    #pragma unroll 10
    for (int t = 0; t < T_STEPS; ++t) {
        const float ir_t = ir[(size_t)t * BN + idx];

        // Bitwise-match reference: u + (-(u-0) + ir)/10 == u + (ir-u)/10.0f
        // (IEEE f32 division, no mul -> no FMA contraction hazard)
        u = u + (ir_t - u) / 10.0f;

        const float o = ((u - 1.0f) >= 0.0f) ? 1.0f : 0.0f;
        __builtin_nontemporal_store(o, &out[(size_t)t * BN + idx]);
        // u_next = u_t + u_rest * o_t = u_t  (u_rest == 0)
    }
}

extern "C" void kernel_launch(void* const* d_in, const int* in_sizes, int n_in,
                              void* d_out, int out_size, void* d_ws, size_t ws_size,
                              hipStream_t stream) {
    const float* ir = (const float*)d_in[0];   // [T, B, N] f32
    const float* u0 = (const float*)d_in[1];   // [B, N] f32
    float* out = (float*)d_out;                // [T, B, N] f32

    lif_fwd<<<dim3(NTHR / 256), dim3(256), 0, stream>>>(ir, u0, out);
}

// Round 4
// 31.095 us; speedup vs baseline: 1.5279x; 1.4290x over previous
//
#include <hip/hip_runtime.h>

// LIF forward: u_t = u + (ir_t - u)/10 ; o_t = 1[u_t >= 1] ; u_rest=0 -> no reset.
// R4: VEC=4 via clang ext_vector_type (true vector type -> nontemporal builtin
// accepts it; HIP_vector_type float4 is a struct and is rejected).
// 16 B/lane loads/stores (m13 6.3 TB/s copy pattern); 65536 threads = 4 waves/CU;
// 4 independent u-chains/thread + unroll 10 give ILP-based latency hiding.
// Exact IEEE f32 divide by 10.0f -> bitwise-identical to numpy ref (absmax 0.0).

#define T_STEPS 100
#define BN      262144        // B*N = 32*8192
#define VEC     4
#define NTHR    (BN / VEC)    // 65536 threads

typedef float f32x4 __attribute__((ext_vector_type(4)));

__global__ __launch_bounds__(256) void lif_fwd(const f32x4* __restrict__ ir,
                                               const f32x4* __restrict__ u0,
                                               f32x4* __restrict__ out) {
    const int idx = blockIdx.x * blockDim.x + threadIdx.x;   // 0..NTHR-1
    const int stride = BN / VEC;                             // f32x4 per time slab

    f32x4 u = u0[idx];

    #pragma unroll 10
    for (int t = 0; t < T_STEPS; ++t) {
        const f32x4 ir_t = ir[(size_t)t * stride + idx];

        // Bitwise-match reference: u + (-(u-0) + ir)/10 == u + (ir-u)/10.0f
        // (IEEE f32 division, no mul -> no FMA contraction hazard)
        f32x4 o;
        #pragma unroll
        for (int j = 0; j < VEC; ++j) {
            u[j] = u[j] + (ir_t[j] - u[j]) / 10.0f;
            o[j] = ((u[j] - 1.0f) >= 0.0f) ? 1.0f : 0.0f;
        }
        __builtin_nontemporal_store(o, &out[(size_t)t * stride + idx]);
        // u_next = u_t + u_rest * o_t = u_t  (u_rest == 0)
    }
}

extern "C" void kernel_launch(void* const* d_in, const int* in_sizes, int n_in,
                              void* d_out, int out_size, void* d_ws, size_t ws_size,
                              hipStream_t stream) {
    const f32x4* ir = (const f32x4*)d_in[0];   // [T, B, N] f32
    const f32x4* u0 = (const f32x4*)d_in[1];   // [B, N] f32
    f32x4* out = (f32x4*)d_out;                // [T, B, N] f32

    lif_fwd<<<dim3(NTHR / 256), dim3(256), 0, stream>>>(ir, u0, out);
}